// Round 11
// baseline (262.670 us; speedup 1.0000x reference)
//
#include <hip/hip_runtime.h>

#define KDIM 8192
#define NDIM 16384
#define BDIM 16
#define NBLK 8                        // KDIM/1024 scale blocks per row
#define TN 8                          // output rows per wave
#define WAVES 4
#define ROWS_PER_BLOCK (WAVES * TN)   // 32
#define SLICE 1024                    // k per block (== one scale block)
#define KC 256                        // k per chunk (64 lanes * 4)

// global->LDS direct copy, 16B/lane: LDS dest wave-uniform, global src per-lane.
__device__ __forceinline__ void gload_lds16(const float* g, float* l) {
    __builtin_amdgcn_global_load_lds(
        (const __attribute__((address_space(1))) unsigned int*)(uintptr_t)g,
        (__attribute__((address_space(3))) unsigned int*)(uintptr_t)l,
        16, 0, 0);
}

// K-split partial GEMM: block = 32 N-rows x one 1024-k slice. x-slice staged
// to LDS ONCE (single barrier), then the W stream runs with ZERO barriers --
// wave-local counted vmcnt only, waves drift, HBM queue never drains.
// launch_bounds(256) with NO min-waves arg (measured: (256,4)->64 VGPR,
// (256,2)->128, none->64 -- all spill; (256)->live-set-driven, no spill).
__global__ __launch_bounds__(256) void int8lin_partial(
    const float* __restrict__ x,
    const int* __restrict__ qw,
    const float* __restrict__ scales,
    float* __restrict__ part)         // [8][16][NDIM]
{
    __shared__ float xs[BDIM][SLICE];   // 64 KB

    const int lane = threadIdx.x & 63;
    const int wave = threadIdx.x >> 6;
    const int s = blockIdx.y;
    const int n0 = blockIdx.x * ROWS_PER_BLOCK + wave * TN;
    const int k0 = s * SLICE;
    const int kbase = lane * 4;

    // Stage x[0..15][k0..k0+1024): wave stages rows 4w..4w+3, 4 passes each.
#pragma unroll
    for (int q = 0; q < 4; ++q) {
        const int r = wave * 4 + q;
#pragma unroll
        for (int p = 0; p < 4; ++p)
            gload_lds16(x + (size_t)r * KDIM + k0 + p * KC + kbase, &xs[r][p * KC]);
    }

    // Prefetch first two W chunks + scales; the barrier's drain covers them.
    const int* wp = qw + (size_t)n0 * KDIM + k0 + kbase;
    int4 wA[TN], wB[TN];
#pragma unroll
    for (int j = 0; j < TN; ++j) wA[j] = *reinterpret_cast<const int4*>(wp + (size_t)j * KDIM);
#pragma unroll
    for (int j = 0; j < TN; ++j) wB[j] = *reinterpret_cast<const int4*>(wp + (size_t)j * KDIM + KC);

    float sc[TN];
#pragma unroll
    for (int j = 0; j < TN; ++j) sc[j] = scales[(size_t)(n0 + j) * NBLK + s];

    float acc[BDIM][TN];
#pragma unroll
    for (int i = 0; i < BDIM; ++i)
#pragma unroll
        for (int j = 0; j < TN; ++j) acc[i][j] = 0.f;

    __syncthreads();   // xs ready for all waves (also lands wA/wB/sc)

    auto C = [&](const int4* w, int c) {
        float wf[TN][4];
#pragma unroll
        for (int j = 0; j < TN; ++j) {
            wf[j][0] = (float)w[j].x * sc[j];
            wf[j][1] = (float)w[j].y * sc[j];
            wf[j][2] = (float)w[j].z * sc[j];
            wf[j][3] = (float)w[j].w * sc[j];
        }
#pragma unroll
        for (int i = 0; i < BDIM; ++i) {
            const float4 xv = *reinterpret_cast<const float4*>(&xs[i][c * KC + kbase]);
#pragma unroll
            for (int j = 0; j < TN; ++j) {
                acc[i][j] = fmaf(xv.x, wf[j][0], acc[i][j]);
                acc[i][j] = fmaf(xv.y, wf[j][1], acc[i][j]);
                acc[i][j] = fmaf(xv.z, wf[j][2], acc[i][j]);
                acc[i][j] = fmaf(xv.w, wf[j][3], acc[i][j]);
            }
        }
    };

    // Barrier-free 2-deep stream over the slice's 4 chunks.
    C(wA, 0);
#pragma unroll
    for (int j = 0; j < TN; ++j) wA[j] = *reinterpret_cast<const int4*>(wp + (size_t)j * KDIM + 2 * KC);
    C(wB, 1);
#pragma unroll
    for (int j = 0; j < TN; ++j) wB[j] = *reinterpret_cast<const int4*>(wp + (size_t)j * KDIM + 3 * KC);
    C(wA, 2);
    C(wB, 3);

    // 64-lane butterfly reduction; lane 0 stores the wave's 16xTN partial tile.
#pragma unroll
    for (int i = 0; i < BDIM; ++i)
#pragma unroll
        for (int j = 0; j < TN; ++j) {
            float v = acc[i][j];
#pragma unroll
            for (int off = 32; off >= 1; off >>= 1) v += __shfl_xor(v, off, 64);
            acc[i][j] = v;
        }

    if (lane == 0) {
#pragma unroll
        for (int i = 0; i < BDIM; ++i)
#pragma unroll
            for (int j = 0; j < TN; ++j)
                part[((size_t)(s * BDIM + i) << 14) + (n0 + j)] = acc[i][j];
    }
}

// out[i][n] = sum_s part[s][i][n] + bias[n]
__global__ __launch_bounds__(256) void int8lin_reduce(
    const float* __restrict__ part,
    const float* __restrict__ bias,
    float* __restrict__ out)
{
    const int idx = blockIdx.x * 256 + threadIdx.x;   // i*NDIM + n
    const int n = idx & (NDIM - 1);
    const int i = idx >> 14;
    float v = bias[n];
#pragma unroll
    for (int s = 0; s < NBLK; ++s)
        v += part[((size_t)(s * BDIM + i) << 14) + n];
    out[idx] = v;
}

// Safety-net fallback (no workspace): lane-per-row direct, slow but correct.
__global__ __launch_bounds__(256) void int8lin_direct(
    const float* __restrict__ x, const int* __restrict__ qw,
    const float* __restrict__ scales, const float* __restrict__ bias,
    float* __restrict__ out)
{
    const int n = blockIdx.x * 256 + threadIdx.x;
    float acc[BDIM];
#pragma unroll
    for (int i = 0; i < BDIM; ++i) acc[i] = 0.f;
    const int* wp = qw + (size_t)n * KDIM;
    for (int kb = 0; kb < KDIM; kb += 1024) {
        const float s = scales[n * NBLK + (kb >> 10)];
        for (int kk = 0; kk < 1024; kk += 4) {
            const int4 w = *reinterpret_cast<const int4*>(wp + kb + kk);
            const float w0 = (float)w.x * s, w1 = (float)w.y * s;
            const float w2 = (float)w.z * s, w3 = (float)w.w * s;
#pragma unroll
            for (int i = 0; i < BDIM; ++i) {
                const float4 xv = *reinterpret_cast<const float4*>(x + (size_t)i * KDIM + kb + kk);
                acc[i] = fmaf(xv.x, w0, fmaf(xv.y, w1, fmaf(xv.z, w2, fmaf(xv.w, w3, acc[i]))));
            }
        }
    }
    const float b = bias[n];
#pragma unroll
    for (int i = 0; i < BDIM; ++i) out[(size_t)i * NDIM + n] = acc[i] + b;
}

extern "C" void kernel_launch(void* const* d_in, const int* in_sizes, int n_in,
                              void* d_out, int out_size, void* d_ws, size_t ws_size,
                              hipStream_t stream) {
    const float* x      = (const float*)d_in[0];
    const int*   qw     = (const int*)d_in[1];
    const float* scales = (const float*)d_in[2];
    const float* bias   = (const float*)d_in[3];
    float*       out    = (float*)d_out;

    const size_t need = (size_t)NBLK * BDIM * NDIM * sizeof(float);   // 8 MB

    if (ws_size >= need) {
        float* part = (float*)d_ws;
        dim3 grid(NDIM / ROWS_PER_BLOCK, NBLK);   // (512, 8)
        int8lin_partial<<<grid, 256, 0, stream>>>(x, qw, scales, part);
        int8lin_reduce<<<(BDIM * NDIM) / 256, 256, 0, stream>>>(part, bias, out);
    } else {
        int8lin_direct<<<NDIM / 256, 256, 0, stream>>>(x, qw, scales, bias, out);
    }
}